// Round 8
// baseline (114.935 us; speedup 1.0000x reference)
//
#include <hip/hip_runtime.h>
#include <hip/hip_bf16.h>

#define NN 65536   // N*N rows
#define DD 128
#define NH 4
#define HDIM 32

typedef __bf16 bf16_t;
typedef __bf16 bf16x8 __attribute__((ext_vector_type(8)));
typedef __bf16 bf16x4 __attribute__((ext_vector_type(4)));
typedef __bf16 bf16x2 __attribute__((ext_vector_type(2)));
typedef float f32x4 __attribute__((ext_vector_type(4)));
typedef float f32x16 __attribute__((ext_vector_type(16)));
typedef unsigned int u32;
typedef unsigned int u32x4 __attribute__((ext_vector_type(4)));

__device__ inline u32 pk2(float a, float b) {
    bf16x2 t;
    t[0] = (bf16_t)a;
    t[1] = (bf16_t)b;
    return __builtin_bit_cast(u32, t);
}
__device__ inline bf16x8 frag4(u32 a, u32 b, u32 c, u32 d) {
    u32x4 t = {a, b, c, d};
    return __builtin_bit_cast(bf16x8, t);
}
__device__ inline bf16x8 cat44(bf16x4 a, bf16x4 b) {
    bf16x8 r;
#pragma unroll
    for (int j = 0; j < 4; j++) { r[j] = a[j]; r[4 + j] = b[j]; }
    return r;
}
// VERIFIED (R2-R6): pack C-layout (col=lane&31, c=(r&3)+8*(r>>2)+4*hi) into two
// contiguous frags via shfl. f0 = lane's c[hi*8..+8), f1 = c[16+hi*8..+8).
__device__ inline void packX(const f32x16& s, bool lo, bf16x8& f0, bf16x8& f1) {
    u32 wv[8];
#pragma unroll
    for (int g = 0; g < 4; g++) {
        wv[2 * g] = pk2(s[4 * g], s[4 * g + 1]);
        wv[2 * g + 1] = pk2(s[4 * g + 2], s[4 * g + 3]);
    }
    u32 p0 = __shfl_xor(wv[0], 32), p1 = __shfl_xor(wv[1], 32);
    u32 p2 = __shfl_xor(wv[2], 32), p3 = __shfl_xor(wv[3], 32);
    u32 p4 = __shfl_xor(wv[4], 32), p5 = __shfl_xor(wv[5], 32);
    u32 p6 = __shfl_xor(wv[6], 32), p7 = __shfl_xor(wv[7], 32);
    f0 = frag4(lo ? wv[0] : p2, lo ? wv[1] : p3, lo ? p0 : wv[2], lo ? p1 : wv[3]);
    f1 = frag4(lo ? wv[4] : p6, lo ? wv[5] : p7, lo ? p4 : wv[6], lo ? p5 : wv[7]);
}

// ---------------- weight transpose + bf16 cast: Wt[m][out][in] ----------------
__global__ __launch_bounds__(128) void convw_kernel(const float* __restrict__ w0,
                                                    const float* __restrict__ w1,
                                                    const float* __restrict__ w2,
                                                    const float* __restrict__ w3,
                                                    const float* __restrict__ w4,
                                                    bf16_t* __restrict__ wt) {
    int m = blockIdx.x >> 7;
    int o = blockIdx.x & 127;
    int d = threadIdx.x;
    const float* W = (m == 0) ? w0 : (m == 1) ? w1 : (m == 2) ? w2 : (m == 3) ? w3 : w4;
    wt[(m * 128 + o) * 128 + d] = (bf16_t)W[d * 128 + o];
}

// ---------------- LayerNorm + fused triangle bias (natural order) ----------------
__global__ __launch_bounds__(256) void ln_kernel(const float* __restrict__ x,
                                                 const float* __restrict__ lw,
                                                 const float* __restrict__ lb,
                                                 const float* __restrict__ Wb,
                                                 bf16_t* __restrict__ z,
                                                 float* __restrict__ bias3) {
    __shared__ float bias_s[4][8];
    int t = threadIdx.x;
    int wv = t >> 6, lane = t & 63;
    int sub = lane >> 5, l32 = lane & 31;
    int rowbase = blockIdx.x * 8;
    int row = rowbase + wv * 2 + sub;
    int d0 = l32 * 4;
    f32x4 v = *reinterpret_cast<const f32x4*>(&x[row * 128 + d0]);
    float s1 = v[0] + v[1] + v[2] + v[3];
    float s2 = v[0] * v[0] + v[1] * v[1] + v[2] * v[2] + v[3] * v[3];
#pragma unroll
    for (int m = 1; m < 32; m <<= 1) {
        s1 += __shfl_xor(s1, m);
        s2 += __shfl_xor(s2, m);
    }
    float mu = s1 * (1.0f / 128.0f);
    float var = s2 * (1.0f / 128.0f) - mu * mu;
    float rs = rsqrtf(var + 1e-5f);
    f32x4 lwv = *reinterpret_cast<const f32x4*>(&lw[d0]);
    f32x4 lbv = *reinterpret_cast<const f32x4*>(&lb[d0]);
    float zv[4];
    bf16x4 pk;
#pragma unroll
    for (int j = 0; j < 4; j++) {
        zv[j] = (v[j] - mu) * rs * lwv[j] + lbv[j];
        pk[j] = (bf16_t)zv[j];
    }
    *reinterpret_cast<bf16x4*>(&z[row * 128 + d0]) = pk;
    f32x4 pb = {0.f, 0.f, 0.f, 0.f};
#pragma unroll
    for (int j = 0; j < 4; j++) {
        f32x4 wbj = *reinterpret_cast<const f32x4*>(&Wb[(d0 + j) * 4]);
#pragma unroll
        for (int hh = 0; hh < 4; hh++) pb[hh] += zv[j] * wbj[hh];
    }
#pragma unroll
    for (int m = 1; m < 32; m <<= 1) {
#pragma unroll
        for (int hh = 0; hh < 4; hh++) pb[hh] += __shfl_xor(pb[hh], m);
    }
    if (l32 == 0) {
#pragma unroll
        for (int hh = 0; hh < 4; hh++)
            bias_s[hh][wv * 2 + sub] = pb[hh] * 1.4426950408889634f;
    }
    __syncthreads();
    if (t < 32) {
        int hh = t >> 3, rl = t & 7;
        bias3[hh * NN + rowbase + rl] = bias_s[hh][rl];
    }
}

// ---------------- bias transpose: bias2[h][k][q] = bias3[h][q*256+k] ----------------
__global__ __launch_bounds__(256) void biastr_kernel(const float* __restrict__ bias3,
                                                     float* __restrict__ bias2) {
    __shared__ float T[64][68];
    int t = threadIdx.x;
    int h = blockIdx.x >> 4;
    int q0 = ((blockIdx.x >> 2) & 3) * 64, k0 = (blockIdx.x & 3) * 64;
#pragma unroll
    for (int i = 0; i < 4; i++) {
        int id = i * 256 + t;
        int r = id >> 4, cb = id & 15;
        f32x4 val = *reinterpret_cast<const f32x4*>(&bias3[h * NN + (q0 + r) * 256 + k0 + cb * 4]);
        *reinterpret_cast<f32x4*>(&T[r][cb * 4]) = val;
    }
    __syncthreads();
#pragma unroll
    for (int i = 0; i < 4; i++) {
        int id = i * 256 + t;
        int kr = id >> 4, qb = id & 15;
        f32x4 o;
#pragma unroll
        for (int j = 0; j < 4; j++) o[j] = T[qb * 4 + j][kr];
        *reinterpret_cast<f32x4*>(&bias2[h * NN + (k0 + kr) * 256 + q0 + qb * 4]) = o;
    }
}

// ---------- fused G + QKV projection + flash attention per (b,h) ----------
// z [row][128]; wt[m][out][in]; bias2 [h][key][q]; om2/gm2 head-major [h][row][32]
__global__ __launch_bounds__(256, 4) void fat_kernel(const bf16_t* __restrict__ z,
                                                     const bf16_t* __restrict__ wt,
                                                     const float* __restrict__ bias2,
                                                     bf16_t* __restrict__ om2,
                                                     bf16_t* __restrict__ gm2) {
    __shared__ bf16_t Kh[256][44];   // [key][c] padded -> conflict-free b128
    __shared__ bf16_t Vt[32][268];   // [c][key] padded -> 2-way b64 (free)
    int t = threadIdx.x;
    int b = blockIdx.x >> 2, h = blockIdx.x & 3;
    int w = t >> 6, lane = t & 63;
    int rsel = lane & 31, hi = lane >> 5;
    int hi8 = hi * 8, hi4 = hi * 4;
    bool lo = (hi == 0);
    const float SCL2 = 0.17677669529663687f * 1.4426950408889634f;  // scale * log2(e)
    const bf16_t* zr0 = z + (size_t)(b * 256 + w * 64 + rsel) * 128;
    const bf16_t* zr1 = zr0 + 32 * 128;

    // ---- G phase: g = sigmoid(z @ Wg[:, h*32..]) for this wave's 64 rows ----
    {
        const bf16_t* wgr = wt + (size_t)(3 * 128 + h * 32 + rsel) * 128;
        f32x16 ag0, ag1;
#pragma unroll
        for (int i = 0; i < 16; i++) { ag0[i] = 0.f; ag1[i] = 0.f; }
#pragma unroll
        for (int ks = 0; ks < 8; ks++) {
            int d = ks * 16 + hi8;
            bf16x8 zb0 = *reinterpret_cast<const bf16x8*>(zr0 + d);
            bf16x8 zb1 = *reinterpret_cast<const bf16x8*>(zr1 + d);
            bf16x8 ag = *reinterpret_cast<const bf16x8*>(wgr + d);
            ag0 = __builtin_amdgcn_mfma_f32_32x32x16_bf16(ag, zb0, ag0, 0, 0, 0);
            ag1 = __builtin_amdgcn_mfma_f32_32x32x16_bf16(ag, zb1, ag1, 0, 0, 0);
        }
#pragma unroll
        for (int i = 0; i < 16; i++) {
            ag0[i] = 1.0f / (1.0f + __expf(-ag0[i]));
            ag1[i] = 1.0f / (1.0f + __expf(-ag1[i]));
        }
        bf16x8 g0, g1;
        bf16_t* grow = gm2 + ((size_t)h * NN + b * 256 + w * 64 + rsel) * 32;
        packX(ag0, lo, g0, g1);
        *reinterpret_cast<bf16x8*>(grow + hi8) = g0;
        *reinterpret_cast<bf16x8*>(grow + 16 + hi8) = g1;
        packX(ag1, lo, g0, g1);
        *reinterpret_cast<bf16x8*>(grow + 32 * 32 + hi8) = g0;
        *reinterpret_cast<bf16x8*>(grow + 32 * 32 + 16 + hi8) = g1;
    }

    // ---- QKV GEMMs (swapped): C[c, row] ----
    const bf16_t* wqr = wt + (size_t)(0 * 128 + h * 32 + rsel) * 128;
    const bf16_t* wkr = wt + (size_t)(1 * 128 + h * 32 + rsel) * 128;
    const bf16_t* wvr = wt + (size_t)(2 * 128 + h * 32 + rsel) * 128;
    f32x16 aq0, aq1, ak0, ak1, av0, av1;
#pragma unroll
    for (int i = 0; i < 16; i++) {
        aq0[i] = 0.f; aq1[i] = 0.f; ak0[i] = 0.f;
        ak1[i] = 0.f; av0[i] = 0.f; av1[i] = 0.f;
    }
#pragma unroll
    for (int ks = 0; ks < 8; ks++) {
        int d = ks * 16 + hi8;
        bf16x8 zb0 = *reinterpret_cast<const bf16x8*>(zr0 + d);
        bf16x8 zb1 = *reinterpret_cast<const bf16x8*>(zr1 + d);
        bf16x8 aq = *reinterpret_cast<const bf16x8*>(wqr + d);
        bf16x8 ak = *reinterpret_cast<const bf16x8*>(wkr + d);
        bf16x8 av = *reinterpret_cast<const bf16x8*>(wvr + d);
        aq0 = __builtin_amdgcn_mfma_f32_32x32x16_bf16(aq, zb0, aq0, 0, 0, 0);
        aq1 = __builtin_amdgcn_mfma_f32_32x32x16_bf16(aq, zb1, aq1, 0, 0, 0);
        ak0 = __builtin_amdgcn_mfma_f32_32x32x16_bf16(ak, zb0, ak0, 0, 0, 0);
        ak1 = __builtin_amdgcn_mfma_f32_32x32x16_bf16(ak, zb1, ak1, 0, 0, 0);
        av0 = __builtin_amdgcn_mfma_f32_32x32x16_bf16(av, zb0, av0, 0, 0, 0);
        av1 = __builtin_amdgcn_mfma_f32_32x32x16_bf16(av, zb1, av1, 0, 0, 0);
    }
    // K -> LDS (packed b128 writes, attn A-frag layout)
    {
        bf16x8 f0, f1;
        int key0 = w * 64 + rsel;
        packX(ak0, lo, f0, f1);
        *reinterpret_cast<bf16x8*>(&Kh[key0][hi8]) = f0;
        *reinterpret_cast<bf16x8*>(&Kh[key0][16 + hi8]) = f1;
        packX(ak1, lo, f0, f1);
        *reinterpret_cast<bf16x8*>(&Kh[key0 + 32][hi8]) = f0;
        *reinterpret_cast<bf16x8*>(&Kh[key0 + 32][16 + hi8]) = f1;
    }
    // V -> LDS transposed (scalar b16 stores, identity key order)
    {
        int key0 = w * 64 + rsel;
#pragma unroll
        for (int r = 0; r < 16; r++) {
            int c = (r & 3) + 8 * (r >> 2) + hi4;
            Vt[c][key0] = (bf16_t)av0[r];
            Vt[c][key0 + 32] = (bf16_t)av1[r];
        }
    }
    // Q -> register B-frags
    bf16x8 qf[2][2];
    packX(aq0, lo, qf[0][0], qf[0][1]);
    packX(aq1, lo, qf[1][0], qf[1][1]);
    __syncthreads();

    // ---- flash attention ----
#pragma unroll
    for (int qt = 0; qt < 2; qt++) {
        int qpos = w * 64 + qt * 32 + rsel;
        bf16x8 qf0 = qf[qt][0];
        bf16x8 qf1 = qf[qt][1];
        const float* bq = bias2 + (size_t)h * NN + qpos;  // + key*256

        f32x16 of;
#pragma unroll
        for (int i = 0; i < 16; i++) of[i] = 0.f;
        float m = -1e30f, l = 0.f;

        float bv[16];
#pragma unroll
        for (int e = 0; e < 16; e++) {
            int key = 8 * (e >> 2) + hi4 + (e & 3);
            bv[e] = bq[(size_t)key * 256];
        }
#pragma unroll
        for (int kt = 0; kt < 8; kt++) {
            bf16x8 k0 = *reinterpret_cast<bf16x8*>(&Kh[kt * 32 + rsel][hi8]);
            bf16x8 k1 = *reinterpret_cast<bf16x8*>(&Kh[kt * 32 + rsel][16 + hi8]);
            f32x16 s;
#pragma unroll
            for (int i = 0; i < 16; i++) s[i] = 0.f;
            __builtin_amdgcn_s_setprio(1);
            s = __builtin_amdgcn_mfma_f32_32x32x16_bf16(k0, qf0, s, 0, 0, 0);
            s = __builtin_amdgcn_mfma_f32_32x32x16_bf16(k1, qf1, s, 0, 0, 0);
            __builtin_amdgcn_s_setprio(0);
            // prefetch next chunk's bias
            float bvn[16];
            if (kt < 7) {
#pragma unroll
                for (int e = 0; e < 16; e++) {
                    int key = (kt + 1) * 32 + 8 * (e >> 2) + hi4 + (e & 3);
                    bvn[e] = bq[(size_t)key * 256];
                }
            }
            float tm[8];
#pragma unroll
            for (int e = 0; e < 16; e++) s[e] = s[e] * SCL2 + bv[e];
#pragma unroll
            for (int e = 0; e < 8; e++) tm[e] = fmaxf(s[e], s[e + 8]);
#pragma unroll
            for (int st = 4; st >= 1; st >>= 1)
#pragma unroll
                for (int e = 0; e < st; e++) tm[e] = fmaxf(tm[e], tm[e + st]);
            float pm = fmaxf(tm[0], __shfl_xor(tm[0], 32));
            // exact defer-max: rescale only if some lane's max grew
            if (__any(pm > m)) {
                float nm = fmaxf(m, pm);
                float al = __builtin_amdgcn_exp2f(m - nm);
                m = nm;
                l *= al;
#pragma unroll
                for (int i = 0; i < 16; i++) of[i] *= al;
            }
            float ts[8];
#pragma unroll
            for (int e = 0; e < 16; e++) s[e] = __builtin_amdgcn_exp2f(s[e] - m);
#pragma unroll
            for (int e = 0; e < 8; e++) ts[e] = s[e] + s[e + 8];
#pragma unroll
            for (int st = 4; st >= 1; st >>= 1)
#pragma unroll
                for (int e = 0; e < st; e++) ts[e] += ts[e + st];
            l += ts[0];
            // P fragments in native C-layout key order (no cross-lane pack):
            // pf0 keys {4hi+0..3, 8+4hi+0..3}, pf1 keys {16+4hi+0..3, 24+4hi+0..3}
            bf16x8 pf0 = frag4(pk2(s[0], s[1]), pk2(s[2], s[3]),
                               pk2(s[4], s[5]), pk2(s[6], s[7]));
            bf16x8 pf1 = frag4(pk2(s[8], s[9]), pk2(s[10], s[11]),
                               pk2(s[12], s[13]), pk2(s[14], s[15]));
            // V fragments with the SAME key order: paired b64 reads
            bf16x8 va = cat44(*reinterpret_cast<bf16x4*>(&Vt[rsel][kt * 32 + hi4]),
                              *reinterpret_cast<bf16x4*>(&Vt[rsel][kt * 32 + 8 + hi4]));
            bf16x8 vb = cat44(*reinterpret_cast<bf16x4*>(&Vt[rsel][kt * 32 + 16 + hi4]),
                              *reinterpret_cast<bf16x4*>(&Vt[rsel][kt * 32 + 24 + hi4]));
            __builtin_amdgcn_s_setprio(1);
            of = __builtin_amdgcn_mfma_f32_32x32x16_bf16(va, pf0, of, 0, 0, 0);
            of = __builtin_amdgcn_mfma_f32_32x32x16_bf16(vb, pf1, of, 0, 0, 0);
            __builtin_amdgcn_s_setprio(0);
            if (kt < 7) {
#pragma unroll
                for (int e = 0; e < 16; e++) bv[e] = bvn[e];
            }
        }

        l += __shfl_xor(l, 32);
        float linv = 1.0f / l;
#pragma unroll
        for (int i = 0; i < 16; i++) of[i] *= linv;
        bf16x8 o0, o1;
        packX(of, lo, o0, o1);
        bf16_t* orow = om2 + ((size_t)h * NN + b * 256 + qpos) * 32;
        *reinterpret_cast<bf16x8*>(orow + hi8) = o0;
        *reinterpret_cast<bf16x8*>(orow + 16 + hi8) = o1;
    }
}

// ---------------- final: out = (o*g) @ Wo, fp32 out, LDS-staged epilogue ----------
__global__ __launch_bounds__(256) void final_kernel(const bf16_t* __restrict__ om2,
                                                    const bf16_t* __restrict__ gm2,
                                                    const bf16_t* __restrict__ wot,
                                                    float* __restrict__ out) {
    __shared__ __align__(16) char smraw[64 * 136 * 2];
    bf16_t(*As)[136] = reinterpret_cast<bf16_t(*)[136]>(smraw);
    float(*Of)[68] = reinterpret_cast<float(*)[68]>(smraw);
    int t = threadIdx.x;
    int rb = blockIdx.x;
#pragma unroll
    for (int i = 0; i < 4; i++) {
        int c = i * 256 + t;
        int r = c >> 4, off = (c & 15) * 8;
        size_t hm = ((size_t)(off >> 5) * NN + rb * 64 + r) * 32 + (off & 31);
        bf16x8 o8 = *reinterpret_cast<const bf16x8*>(&om2[hm]);
        bf16x8 g8 = *reinterpret_cast<const bf16x8*>(&gm2[hm]);
        bf16x8 p8;
#pragma unroll
        for (int e = 0; e < 8; e++) p8[e] = (bf16_t)((float)o8[e] * (float)g8[e]);
        *reinterpret_cast<bf16x8*>(&As[r][off]) = p8;
    }
    __syncthreads();
    int w = t >> 6, lane = t & 63;
    int lx = lane & 15, ly = lane >> 4;
    int m0 = (w >> 1) * 32, n0 = (w & 1) * 32;
    bf16x8 af[2][4];
#pragma unroll
    for (int mt = 0; mt < 2; mt++)
#pragma unroll
        for (int ks = 0; ks < 4; ks++)
            af[mt][ks] = *reinterpret_cast<bf16x8*>(&As[m0 + mt * 16 + lx][ks * 32 + ly * 8]);
    __syncthreads();  // As dead; Of may alias

    for (int half = 0; half < 2; half++) {
        int nc0 = half * 64;
        bf16x8 bfr[2][4];
#pragma unroll
        for (int nt = 0; nt < 2; nt++)
#pragma unroll
            for (int ks = 0; ks < 4; ks++)
                bfr[nt][ks] = *reinterpret_cast<const bf16x8*>(
                    &wot[(nc0 + n0 + nt * 16 + lx) * 128 + ks * 32 + ly * 8]);
        f32x4 acc[2][2];
#pragma unroll
        for (int mt = 0; mt < 2; mt++)
#pragma unroll
            for (int nt = 0; nt < 2; nt++) acc[mt][nt] = (f32x4){0.f, 0.f, 0.f, 0.f};
#pragma unroll
        for (int ks = 0; ks < 4; ks++)
#pragma unroll
            for (int mt = 0; mt < 2; mt++)
#pragma unroll
                for (int nt = 0; nt < 2; nt++)
                    acc[mt][nt] = __builtin_amdgcn_mfma_f32_16x16x32_bf16(af[mt][ks], bfr[nt][ks], acc[mt][nt], 0, 0, 0);
#pragma unroll
        for (int mt = 0; mt < 2; mt++)
#pragma unroll
            for (int nt = 0; nt < 2; nt++)
#pragma unroll
                for (int r = 0; r < 4; r++)
                    Of[m0 + mt * 16 + ly * 4 + r][n0 + nt * 16 + lx] = acc[mt][nt][r];
        __syncthreads();
#pragma unroll
        for (int j = 0; j < 4; j++) {
            int ch = j * 256 + t;
            int r = ch >> 4, cb = ch & 15;
            f32x4 val = *reinterpret_cast<f32x4*>(&Of[r][cb * 4]);
            *reinterpret_cast<f32x4*>(&out[(rb * 64 + r) * 128 + nc0 + cb * 4]) = val;
        }
        __syncthreads();
    }
}

extern "C" void kernel_launch(void* const* d_in, const int* in_sizes, int n_in,
                              void* d_out, int out_size, void* d_ws, size_t ws_size,
                              hipStream_t stream) {
    const float* x   = (const float*)d_in[0];
    const float* lnw = (const float*)d_in[1];
    const float* lnb = (const float*)d_in[2];
    const float* Wb  = (const float*)d_in[3];
    const float* Wq  = (const float*)d_in[4];
    const float* Wk  = (const float*)d_in[5];
    const float* Wv  = (const float*)d_in[6];
    const float* Wg  = (const float*)d_in[7];
    const float* Wo  = (const float*)d_in[8];
    float* out = (float*)d_out;

    char* ws = (char*)d_ws;
    const size_t MAT = (size_t)NN * 128 * sizeof(bf16_t);  // 16 MB
    bf16_t* z     = (bf16_t*)(ws);
    bf16_t* gmat  = (bf16_t*)(ws + MAT);                     // head-major
    bf16_t* omat  = (bf16_t*)(ws + 2 * MAT);                 // head-major
    bf16_t* wt    = (bf16_t*)(ws + 3 * MAT);                 // 5 * 128*128 bf16 = 160KB
    float*  bias3 = (float*)(ws + 3 * MAT + (1 << 20));      // 1MB
    float*  bias2 = (float*)(ws + 3 * MAT + (2 << 20));      // 1MB

    convw_kernel<<<640, 128, 0, stream>>>(Wq, Wk, Wv, Wg, Wo, wt);
    ln_kernel<<<8192, 256, 0, stream>>>(x, lnw, lnb, Wb, z, bias3);
    biastr_kernel<<<64, 256, 0, stream>>>(bias3, bias2);
    fat_kernel<<<1024, 256, 0, stream>>>(z, wt, bias2, omat, gmat);
    final_kernel<<<1024, 256, 0, stream>>>(omat, gmat, wt + 4 * 16384, out);
}

// Round 9
// 98.958 us; speedup vs baseline: 1.1615x; 1.1615x over previous
//
#include <hip/hip_runtime.h>
#include <hip/hip_bf16.h>

#define NN 65536   // N*N rows
#define DD 128
#define NH 4
#define HDIM 32

typedef __bf16 bf16_t;
typedef __bf16 bf16x8 __attribute__((ext_vector_type(8)));
typedef __bf16 bf16x4 __attribute__((ext_vector_type(4)));
typedef __bf16 bf16x2 __attribute__((ext_vector_type(2)));
typedef float f32x4 __attribute__((ext_vector_type(4)));
typedef float f32x16 __attribute__((ext_vector_type(16)));
typedef unsigned int u32;
typedef unsigned int u32x4 __attribute__((ext_vector_type(4)));

__device__ inline u32 pk2(float a, float b) {
    bf16x2 t;
    t[0] = (bf16_t)a;
    t[1] = (bf16_t)b;
    return __builtin_bit_cast(u32, t);
}
__device__ inline bf16x8 frag4(u32 a, u32 b, u32 c, u32 d) {
    u32x4 t = {a, b, c, d};
    return __builtin_bit_cast(bf16x8, t);
}
__device__ inline bf16x8 cat44(bf16x4 a, bf16x4 b) {
    bf16x8 r;
#pragma unroll
    for (int j = 0; j < 4; j++) { r[j] = a[j]; r[4 + j] = b[j]; }
    return r;
}
// VERIFIED (R2-R6): pack C-layout (col=lane&31, c=(r&3)+8*(r>>2)+4*hi) into two
// contiguous frags via shfl. f0 = lane's c[hi*8..+8), f1 = c[16+hi*8..+8).
__device__ inline void packX(const f32x16& s, bool lo, bf16x8& f0, bf16x8& f1) {
    u32 wv[8];
#pragma unroll
    for (int g = 0; g < 4; g++) {
        wv[2 * g] = pk2(s[4 * g], s[4 * g + 1]);
        wv[2 * g + 1] = pk2(s[4 * g + 2], s[4 * g + 3]);
    }
    u32 p0 = __shfl_xor(wv[0], 32), p1 = __shfl_xor(wv[1], 32);
    u32 p2 = __shfl_xor(wv[2], 32), p3 = __shfl_xor(wv[3], 32);
    u32 p4 = __shfl_xor(wv[4], 32), p5 = __shfl_xor(wv[5], 32);
    u32 p6 = __shfl_xor(wv[6], 32), p7 = __shfl_xor(wv[7], 32);
    f0 = frag4(lo ? wv[0] : p2, lo ? wv[1] : p3, lo ? p0 : wv[2], lo ? p1 : wv[3]);
    f1 = frag4(lo ? wv[4] : p6, lo ? wv[5] : p7, lo ? p4 : wv[6], lo ? p5 : wv[7]);
}

// ---------------- weight transpose + bf16 cast: Wt[m][out][in] ----------------
__global__ __launch_bounds__(128) void convw_kernel(const float* __restrict__ w0,
                                                    const float* __restrict__ w1,
                                                    const float* __restrict__ w2,
                                                    const float* __restrict__ w3,
                                                    const float* __restrict__ w4,
                                                    bf16_t* __restrict__ wt) {
    int m = blockIdx.x >> 7;
    int o = blockIdx.x & 127;
    int d = threadIdx.x;
    const float* W = (m == 0) ? w0 : (m == 1) ? w1 : (m == 2) ? w2 : (m == 3) ? w3 : w4;
    wt[(m * 128 + o) * 128 + d] = (bf16_t)W[d * 128 + o];
}

// ---------------- LayerNorm + fused triangle bias (natural order) ----------------
__global__ __launch_bounds__(256) void ln_kernel(const float* __restrict__ x,
                                                 const float* __restrict__ lw,
                                                 const float* __restrict__ lb,
                                                 const float* __restrict__ Wb,
                                                 bf16_t* __restrict__ z,
                                                 float* __restrict__ bias3) {
    __shared__ float bias_s[4][8];
    int t = threadIdx.x;
    int wv = t >> 6, lane = t & 63;
    int sub = lane >> 5, l32 = lane & 31;
    int rowbase = blockIdx.x * 8;
    int row = rowbase + wv * 2 + sub;
    int d0 = l32 * 4;
    f32x4 v = *reinterpret_cast<const f32x4*>(&x[row * 128 + d0]);
    float s1 = v[0] + v[1] + v[2] + v[3];
    float s2 = v[0] * v[0] + v[1] * v[1] + v[2] * v[2] + v[3] * v[3];
#pragma unroll
    for (int m = 1; m < 32; m <<= 1) {
        s1 += __shfl_xor(s1, m);
        s2 += __shfl_xor(s2, m);
    }
    float mu = s1 * (1.0f / 128.0f);
    float var = s2 * (1.0f / 128.0f) - mu * mu;
    float rs = rsqrtf(var + 1e-5f);
    f32x4 lwv = *reinterpret_cast<const f32x4*>(&lw[d0]);
    f32x4 lbv = *reinterpret_cast<const f32x4*>(&lb[d0]);
    float zv[4];
    bf16x4 pk;
#pragma unroll
    for (int j = 0; j < 4; j++) {
        zv[j] = (v[j] - mu) * rs * lwv[j] + lbv[j];
        pk[j] = (bf16_t)zv[j];
    }
    *reinterpret_cast<bf16x4*>(&z[row * 128 + d0]) = pk;
    f32x4 pb = {0.f, 0.f, 0.f, 0.f};
#pragma unroll
    for (int j = 0; j < 4; j++) {
        f32x4 wbj = *reinterpret_cast<const f32x4*>(&Wb[(d0 + j) * 4]);
#pragma unroll
        for (int hh = 0; hh < 4; hh++) pb[hh] += zv[j] * wbj[hh];
    }
#pragma unroll
    for (int m = 1; m < 32; m <<= 1) {
#pragma unroll
        for (int hh = 0; hh < 4; hh++) pb[hh] += __shfl_xor(pb[hh], m);
    }
    if (l32 == 0) {
#pragma unroll
        for (int hh = 0; hh < 4; hh++)
            bias_s[hh][wv * 2 + sub] = pb[hh] * 1.4426950408889634f;
    }
    __syncthreads();
    if (t < 32) {
        int hh = t >> 3, rl = t & 7;
        bias3[hh * NN + rowbase + rl] = bias_s[hh][rl];
    }
}

// ---------------- bias transpose: bias2[h][k][q] = bias3[h][q*256+k] ----------------
__global__ __launch_bounds__(256) void biastr_kernel(const float* __restrict__ bias3,
                                                     float* __restrict__ bias2) {
    __shared__ float T[64][68];
    int t = threadIdx.x;
    int h = blockIdx.x >> 4;
    int q0 = ((blockIdx.x >> 2) & 3) * 64, k0 = (blockIdx.x & 3) * 64;
#pragma unroll
    for (int i = 0; i < 4; i++) {
        int id = i * 256 + t;
        int r = id >> 4, cb = id & 15;
        f32x4 val = *reinterpret_cast<const f32x4*>(&bias3[h * NN + (q0 + r) * 256 + k0 + cb * 4]);
        *reinterpret_cast<f32x4*>(&T[r][cb * 4]) = val;
    }
    __syncthreads();
#pragma unroll
    for (int i = 0; i < 4; i++) {
        int id = i * 256 + t;
        int kr = id >> 4, qb = id & 15;
        f32x4 o;
#pragma unroll
        for (int j = 0; j < 4; j++) o[j] = T[qb * 4 + j][kr];
        *reinterpret_cast<f32x4*>(&bias2[h * NN + (k0 + kr) * 256 + q0 + qb * 4]) = o;
    }
}

// ---------- fused G + QKV projection + flash attention per (b,h) ----------
// z [row][128]; wt[m][out][in]; bias2 [h][key][q]; om2/gm2 head-major [h][row][32]
// launch_bounds (256,3): 3 waves/SIMD -> ~170 unified VGPR+AGPR per wave.
// (256,4) caps at 128 and spills ~60MB to scratch (R8: 93us vs 58us).
__global__ __launch_bounds__(256, 3) void fat_kernel(const bf16_t* __restrict__ z,
                                                     const bf16_t* __restrict__ wt,
                                                     const float* __restrict__ bias2,
                                                     bf16_t* __restrict__ om2,
                                                     bf16_t* __restrict__ gm2) {
    __shared__ bf16_t Kh[256][44];   // [key][c] padded -> conflict-free b128
    __shared__ bf16_t Vt[32][268];   // [c][key] padded -> 2-way b64 (free)
    int t = threadIdx.x;
    int b = blockIdx.x >> 2, h = blockIdx.x & 3;
    int w = t >> 6, lane = t & 63;
    int rsel = lane & 31, hi = lane >> 5;
    int hi8 = hi * 8, hi4 = hi * 4;
    bool lo = (hi == 0);
    const float SCL2 = 0.17677669529663687f * 1.4426950408889634f;  // scale * log2(e)
    const bf16_t* zr0 = z + (size_t)(b * 256 + w * 64 + rsel) * 128;
    const bf16_t* zr1 = zr0 + 32 * 128;

    // ---- G phase: g = sigmoid(z @ Wg[:, h*32..]) for this wave's 64 rows ----
    {
        const bf16_t* wgr = wt + (size_t)(3 * 128 + h * 32 + rsel) * 128;
        f32x16 ag0, ag1;
#pragma unroll
        for (int i = 0; i < 16; i++) { ag0[i] = 0.f; ag1[i] = 0.f; }
#pragma unroll
        for (int ks = 0; ks < 8; ks++) {
            int d = ks * 16 + hi8;
            bf16x8 zb0 = *reinterpret_cast<const bf16x8*>(zr0 + d);
            bf16x8 zb1 = *reinterpret_cast<const bf16x8*>(zr1 + d);
            bf16x8 ag = *reinterpret_cast<const bf16x8*>(wgr + d);
            ag0 = __builtin_amdgcn_mfma_f32_32x32x16_bf16(ag, zb0, ag0, 0, 0, 0);
            ag1 = __builtin_amdgcn_mfma_f32_32x32x16_bf16(ag, zb1, ag1, 0, 0, 0);
        }
#pragma unroll
        for (int i = 0; i < 16; i++) {
            ag0[i] = 1.0f / (1.0f + __expf(-ag0[i]));
            ag1[i] = 1.0f / (1.0f + __expf(-ag1[i]));
        }
        bf16x8 g0, g1;
        bf16_t* grow = gm2 + ((size_t)h * NN + b * 256 + w * 64 + rsel) * 32;
        packX(ag0, lo, g0, g1);
        *reinterpret_cast<bf16x8*>(grow + hi8) = g0;
        *reinterpret_cast<bf16x8*>(grow + 16 + hi8) = g1;
        packX(ag1, lo, g0, g1);
        *reinterpret_cast<bf16x8*>(grow + 32 * 32 + hi8) = g0;
        *reinterpret_cast<bf16x8*>(grow + 32 * 32 + 16 + hi8) = g1;
    }

    // ---- QKV GEMMs (swapped): C[c, row] ----
    const bf16_t* wqr = wt + (size_t)(0 * 128 + h * 32 + rsel) * 128;
    const bf16_t* wkr = wt + (size_t)(1 * 128 + h * 32 + rsel) * 128;
    const bf16_t* wvr = wt + (size_t)(2 * 128 + h * 32 + rsel) * 128;
    f32x16 aq0, aq1, ak0, ak1, av0, av1;
#pragma unroll
    for (int i = 0; i < 16; i++) {
        aq0[i] = 0.f; aq1[i] = 0.f; ak0[i] = 0.f;
        ak1[i] = 0.f; av0[i] = 0.f; av1[i] = 0.f;
    }
#pragma unroll
    for (int ks = 0; ks < 8; ks++) {
        int d = ks * 16 + hi8;
        bf16x8 zb0 = *reinterpret_cast<const bf16x8*>(zr0 + d);
        bf16x8 zb1 = *reinterpret_cast<const bf16x8*>(zr1 + d);
        bf16x8 aq = *reinterpret_cast<const bf16x8*>(wqr + d);
        bf16x8 ak = *reinterpret_cast<const bf16x8*>(wkr + d);
        bf16x8 av = *reinterpret_cast<const bf16x8*>(wvr + d);
        aq0 = __builtin_amdgcn_mfma_f32_32x32x16_bf16(aq, zb0, aq0, 0, 0, 0);
        aq1 = __builtin_amdgcn_mfma_f32_32x32x16_bf16(aq, zb1, aq1, 0, 0, 0);
        ak0 = __builtin_amdgcn_mfma_f32_32x32x16_bf16(ak, zb0, ak0, 0, 0, 0);
        ak1 = __builtin_amdgcn_mfma_f32_32x32x16_bf16(ak, zb1, ak1, 0, 0, 0);
        av0 = __builtin_amdgcn_mfma_f32_32x32x16_bf16(av, zb0, av0, 0, 0, 0);
        av1 = __builtin_amdgcn_mfma_f32_32x32x16_bf16(av, zb1, av1, 0, 0, 0);
    }
    // K -> LDS (packed b128 writes, attn A-frag layout)
    {
        bf16x8 f0, f1;
        int key0 = w * 64 + rsel;
        packX(ak0, lo, f0, f1);
        *reinterpret_cast<bf16x8*>(&Kh[key0][hi8]) = f0;
        *reinterpret_cast<bf16x8*>(&Kh[key0][16 + hi8]) = f1;
        packX(ak1, lo, f0, f1);
        *reinterpret_cast<bf16x8*>(&Kh[key0 + 32][hi8]) = f0;
        *reinterpret_cast<bf16x8*>(&Kh[key0 + 32][16 + hi8]) = f1;
    }
    // V -> LDS transposed (scalar b16 stores, identity key order)
    {
        int key0 = w * 64 + rsel;
#pragma unroll
        for (int r = 0; r < 16; r++) {
            int c = (r & 3) + 8 * (r >> 2) + hi4;
            Vt[c][key0] = (bf16_t)av0[r];
            Vt[c][key0 + 32] = (bf16_t)av1[r];
        }
    }
    // Q -> register B-frags
    bf16x8 qf[2][2];
    packX(aq0, lo, qf[0][0], qf[0][1]);
    packX(aq1, lo, qf[1][0], qf[1][1]);
    __syncthreads();

    // ---- flash attention ----
#pragma unroll
    for (int qt = 0; qt < 2; qt++) {
        int qpos = w * 64 + qt * 32 + rsel;
        bf16x8 qf0 = qf[qt][0];
        bf16x8 qf1 = qf[qt][1];
        const float* bq = bias2 + (size_t)h * NN + qpos;  // + key*256

        f32x16 of;
#pragma unroll
        for (int i = 0; i < 16; i++) of[i] = 0.f;
        float m = -1e30f, l = 0.f;

        float bv[16];
#pragma unroll
        for (int e = 0; e < 16; e++) {
            int key = 8 * (e >> 2) + hi4 + (e & 3);
            bv[e] = bq[(size_t)key * 256];
        }
#pragma unroll
        for (int kt = 0; kt < 8; kt++) {
            bf16x8 k0 = *reinterpret_cast<bf16x8*>(&Kh[kt * 32 + rsel][hi8]);
            bf16x8 k1 = *reinterpret_cast<bf16x8*>(&Kh[kt * 32 + rsel][16 + hi8]);
            f32x16 s;
#pragma unroll
            for (int i = 0; i < 16; i++) s[i] = 0.f;
            __builtin_amdgcn_s_setprio(1);
            s = __builtin_amdgcn_mfma_f32_32x32x16_bf16(k0, qf0, s, 0, 0, 0);
            s = __builtin_amdgcn_mfma_f32_32x32x16_bf16(k1, qf1, s, 0, 0, 0);
            __builtin_amdgcn_s_setprio(0);
            // prefetch next chunk's bias
            float bvn[16];
            if (kt < 7) {
#pragma unroll
                for (int e = 0; e < 16; e++) {
                    int key = (kt + 1) * 32 + 8 * (e >> 2) + hi4 + (e & 3);
                    bvn[e] = bq[(size_t)key * 256];
                }
            }
            float tm[8];
#pragma unroll
            for (int e = 0; e < 16; e++) s[e] = s[e] * SCL2 + bv[e];
#pragma unroll
            for (int e = 0; e < 8; e++) tm[e] = fmaxf(s[e], s[e + 8]);
#pragma unroll
            for (int st = 4; st >= 1; st >>= 1)
#pragma unroll
                for (int e = 0; e < st; e++) tm[e] = fmaxf(tm[e], tm[e + st]);
            float pm = fmaxf(tm[0], __shfl_xor(tm[0], 32));
            // exact defer-max: rescale only if some lane's max grew
            if (__any(pm > m)) {
                float nm = fmaxf(m, pm);
                float al = __builtin_amdgcn_exp2f(m - nm);
                m = nm;
                l *= al;
#pragma unroll
                for (int i = 0; i < 16; i++) of[i] *= al;
            }
            float ts[8];
#pragma unroll
            for (int e = 0; e < 16; e++) s[e] = __builtin_amdgcn_exp2f(s[e] - m);
#pragma unroll
            for (int e = 0; e < 8; e++) ts[e] = s[e] + s[e + 8];
#pragma unroll
            for (int st = 4; st >= 1; st >>= 1)
#pragma unroll
                for (int e = 0; e < st; e++) ts[e] += ts[e + st];
            l += ts[0];
            // P fragments in native C-layout key order (no cross-lane pack):
            // pf0 keys {4hi+0..3, 8+4hi+0..3}, pf1 keys {16+4hi+0..3, 24+4hi+0..3}
            bf16x8 pf0 = frag4(pk2(s[0], s[1]), pk2(s[2], s[3]),
                               pk2(s[4], s[5]), pk2(s[6], s[7]));
            bf16x8 pf1 = frag4(pk2(s[8], s[9]), pk2(s[10], s[11]),
                               pk2(s[12], s[13]), pk2(s[14], s[15]));
            // V fragments with the SAME key order: paired b64 reads
            bf16x8 va = cat44(*reinterpret_cast<bf16x4*>(&Vt[rsel][kt * 32 + hi4]),
                              *reinterpret_cast<bf16x4*>(&Vt[rsel][kt * 32 + 8 + hi4]));
            bf16x8 vb = cat44(*reinterpret_cast<bf16x4*>(&Vt[rsel][kt * 32 + 16 + hi4]),
                              *reinterpret_cast<bf16x4*>(&Vt[rsel][kt * 32 + 24 + hi4]));
            __builtin_amdgcn_s_setprio(1);
            of = __builtin_amdgcn_mfma_f32_32x32x16_bf16(va, pf0, of, 0, 0, 0);
            of = __builtin_amdgcn_mfma_f32_32x32x16_bf16(vb, pf1, of, 0, 0, 0);
            __builtin_amdgcn_s_setprio(0);
            if (kt < 7) {
#pragma unroll
                for (int e = 0; e < 16; e++) bv[e] = bvn[e];
            }
        }

        l += __shfl_xor(l, 32);
        float linv = 1.0f / l;
#pragma unroll
        for (int i = 0; i < 16; i++) of[i] *= linv;
        bf16x8 o0, o1;
        packX(of, lo, o0, o1);
        bf16_t* orow = om2 + ((size_t)h * NN + b * 256 + qpos) * 32;
        *reinterpret_cast<bf16x8*>(orow + hi8) = o0;
        *reinterpret_cast<bf16x8*>(orow + 16 + hi8) = o1;
    }
}

// ---------------- final: out = (o*g) @ Wo, fp32 out, LDS-staged epilogue ----------
__global__ __launch_bounds__(256) void final_kernel(const bf16_t* __restrict__ om2,
                                                    const bf16_t* __restrict__ gm2,
                                                    const bf16_t* __restrict__ wot,
                                                    float* __restrict__ out) {
    __shared__ __align__(16) char smraw[64 * 136 * 2];
    bf16_t(*As)[136] = reinterpret_cast<bf16_t(*)[136]>(smraw);
    float(*Of)[68] = reinterpret_cast<float(*)[68]>(smraw);
    int t = threadIdx.x;
    int rb = blockIdx.x;
#pragma unroll
    for (int i = 0; i < 4; i++) {
        int c = i * 256 + t;
        int r = c >> 4, off = (c & 15) * 8;
        size_t hm = ((size_t)(off >> 5) * NN + rb * 64 + r) * 32 + (off & 31);
        bf16x8 o8 = *reinterpret_cast<const bf16x8*>(&om2[hm]);
        bf16x8 g8 = *reinterpret_cast<const bf16x8*>(&gm2[hm]);
        bf16x8 p8;
#pragma unroll
        for (int e = 0; e < 8; e++) p8[e] = (bf16_t)((float)o8[e] * (float)g8[e]);
        *reinterpret_cast<bf16x8*>(&As[r][off]) = p8;
    }
    __syncthreads();
    int w = t >> 6, lane = t & 63;
    int lx = lane & 15, ly = lane >> 4;
    int m0 = (w >> 1) * 32, n0 = (w & 1) * 32;
    bf16x8 af[2][4];
#pragma unroll
    for (int mt = 0; mt < 2; mt++)
#pragma unroll
        for (int ks = 0; ks < 4; ks++)
            af[mt][ks] = *reinterpret_cast<bf16x8*>(&As[m0 + mt * 16 + lx][ks * 32 + ly * 8]);
    __syncthreads();  // As dead; Of may alias

    for (int half = 0; half < 2; half++) {
        int nc0 = half * 64;
        bf16x8 bfr[2][4];
#pragma unroll
        for (int nt = 0; nt < 2; nt++)
#pragma unroll
            for (int ks = 0; ks < 4; ks++)
                bfr[nt][ks] = *reinterpret_cast<const bf16x8*>(
                    &wot[(nc0 + n0 + nt * 16 + lx) * 128 + ks * 32 + ly * 8]);
        f32x4 acc[2][2];
#pragma unroll
        for (int mt = 0; mt < 2; mt++)
#pragma unroll
            for (int nt = 0; nt < 2; nt++) acc[mt][nt] = (f32x4){0.f, 0.f, 0.f, 0.f};
#pragma unroll
        for (int ks = 0; ks < 4; ks++)
#pragma unroll
            for (int mt = 0; mt < 2; mt++)
#pragma unroll
                for (int nt = 0; nt < 2; nt++)
                    acc[mt][nt] = __builtin_amdgcn_mfma_f32_16x16x32_bf16(af[mt][ks], bfr[nt][ks], acc[mt][nt], 0, 0, 0);
#pragma unroll
        for (int mt = 0; mt < 2; mt++)
#pragma unroll
            for (int nt = 0; nt < 2; nt++)
#pragma unroll
                for (int r = 0; r < 4; r++)
                    Of[m0 + mt * 16 + ly * 4 + r][n0 + nt * 16 + lx] = acc[mt][nt][r];
        __syncthreads();
#pragma unroll
        for (int j = 0; j < 4; j++) {
            int ch = j * 256 + t;
            int r = ch >> 4, cb = ch & 15;
            f32x4 val = *reinterpret_cast<f32x4*>(&Of[r][cb * 4]);
            *reinterpret_cast<f32x4*>(&out[(rb * 64 + r) * 128 + nc0 + cb * 4]) = val;
        }
        __syncthreads();
    }
}

extern "C" void kernel_launch(void* const* d_in, const int* in_sizes, int n_in,
                              void* d_out, int out_size, void* d_ws, size_t ws_size,
                              hipStream_t stream) {
    const float* x   = (const float*)d_in[0];
    const float* lnw = (const float*)d_in[1];
    const float* lnb = (const float*)d_in[2];
    const float* Wb  = (const float*)d_in[3];
    const float* Wq  = (const float*)d_in[4];
    const float* Wk  = (const float*)d_in[5];
    const float* Wv  = (const float*)d_in[6];
    const float* Wg  = (const float*)d_in[7];
    const float* Wo  = (const float*)d_in[8];
    float* out = (float*)d_out;

    char* ws = (char*)d_ws;
    const size_t MAT = (size_t)NN * 128 * sizeof(bf16_t);  // 16 MB
    bf16_t* z     = (bf16_t*)(ws);
    bf16_t* gmat  = (bf16_t*)(ws + MAT);                     // head-major
    bf16_t* omat  = (bf16_t*)(ws + 2 * MAT);                 // head-major
    bf16_t* wt    = (bf16_t*)(ws + 3 * MAT);                 // 5 * 128*128 bf16 = 160KB
    float*  bias3 = (float*)(ws + 3 * MAT + (1 << 20));      // 1MB
    float*  bias2 = (float*)(ws + 3 * MAT + (2 << 20));      // 1MB

    convw_kernel<<<640, 128, 0, stream>>>(Wq, Wk, Wv, Wg, Wo, wt);
    ln_kernel<<<8192, 256, 0, stream>>>(x, lnw, lnb, Wb, z, bias3);
    biastr_kernel<<<64, 256, 0, stream>>>(bias3, bias2);
    fat_kernel<<<1024, 256, 0, stream>>>(z, wt, bias2, omat, gmat);
    final_kernel<<<1024, 256, 0, stream>>>(omat, gmat, wt + 4 * 16384, out);
}